// Round 2
// baseline (80.356 us; speedup 1.0000x reference)
//
#include <hip/hip_runtime.h>
#include <hip/hip_bf16.h>

// x:      (8, 3, 512, 512) fp32
// shift:  (16, 3) fp32
// slopes: (16, 3) fp32
// conv_w: (3,)  fp32
// conv_b: (1,)  fp32
// out:    (8, 1, 512, 512) fp32
//
// out[b,h,w] = clip( conv_b + sum_c conv_w[c] * sum_p slopes[p,c]*relu(x[b,c,h,w]-shift[p,c]), 0, 1 )

constexpr int NPTS = 16;
constexpr int C    = 3;
constexpr int HW   = 512 * 512;   // 262144 = 2^18
constexpr int HW4  = HW / 4;      // 65536 = 2^16

__global__ __launch_bounds__(256)
void curve_channel_kernel(const float4* __restrict__ x,
                          const float*  __restrict__ shift,   // (NPTS, C)
                          const float*  __restrict__ slopes,  // (NPTS, C)
                          const float*  __restrict__ conv_w,  // (C,)
                          const float*  __restrict__ conv_b,  // (1,)
                          float4*       __restrict__ out,
                          int n4)                              // total float4 outputs
{
    const int idx = blockIdx.x * 256 + threadIdx.x;   // float4 index in [0, n4)
    if (idx >= n4) return;

    const int b   = idx >> 16;                        // idx / HW4  (HW4 = 2^16)
    const int hw4 = idx & (HW4 - 1);                  // idx % HW4

    const float4* xb = x + (size_t)b * (C * HW4) + hw4;

    const float bias = conv_b[0];
    float ax = bias, ay = bias, az = bias, aw = bias;

#pragma unroll
    for (int c = 0; c < C; ++c) {
        const float4 xv = xb[(size_t)c * HW4];
        const float  w  = conv_w[c];
        float yx = 0.f, yy = 0.f, yz = 0.f, yw = 0.f;
#pragma unroll
        for (int p = 0; p < NPTS; ++p) {
            const float s = shift[p * C + c];   // wave-uniform -> scalar load
            const float m = slopes[p * C + c];
            yx += m * fmaxf(xv.x - s, 0.f);
            yy += m * fmaxf(xv.y - s, 0.f);
            yz += m * fmaxf(xv.z - s, 0.f);
            yw += m * fmaxf(xv.w - s, 0.f);
        }
        ax += w * yx;
        ay += w * yy;
        az += w * yz;
        aw += w * yw;
    }

    float4 o;
    o.x = fminf(fmaxf(ax, 0.f), 1.f);
    o.y = fminf(fmaxf(ay, 0.f), 1.f);
    o.z = fminf(fmaxf(az, 0.f), 1.f);
    o.w = fminf(fmaxf(aw, 0.f), 1.f);
    out[idx] = o;
}

extern "C" void kernel_launch(void* const* d_in, const int* in_sizes, int n_in,
                              void* d_out, int out_size, void* d_ws, size_t ws_size,
                              hipStream_t stream)
{
    const float* x      = (const float*)d_in[0];
    const float* shift  = (const float*)d_in[1];
    const float* slopes = (const float*)d_in[2];
    const float* conv_w = (const float*)d_in[3];
    const float* conv_b = (const float*)d_in[4];
    float*       out    = (float*)d_out;

    const int n4     = out_size / 4;              // float4 outputs
    const int blocks = (n4 + 255) / 256;

    curve_channel_kernel<<<dim3(blocks), dim3(256), 0, stream>>>(
        (const float4*)x, shift, slopes, conv_w, conv_b, (float4*)out, n4);
}